// Round 7
// baseline (258.122 us; speedup 1.0000x reference)
//
#include <hip/hip_runtime.h>
#include <hip/hip_bf16.h>
#include <stdint.h>
#include <stddef.h>

using short8  = __attribute__((ext_vector_type(8))) short;
using short4v = __attribute__((ext_vector_type(4))) short;
using int4v   = __attribute__((ext_vector_type(4))) int;
using f32x4   = __attribute__((ext_vector_type(4))) float;
typedef __hip_bfloat16 bf16_t;

__device__ __forceinline__ void glds16(const void* g, const void* l) {
  __builtin_amdgcn_global_load_lds(
      (const __attribute__((address_space(1))) void*)g,
      (__attribute__((address_space(3))) void*)l, 16, 0, 0);
}
__device__ __forceinline__ short bfbits(float x) {
  bf16_t h = __float2bfloat16(x);
  return __builtin_bit_cast(short, h);
}
// pack two fp32 -> two bf16 (RTZ) in one v_perm_b32
__device__ __forceinline__ int pk2(float lo, float hi) {
  return __builtin_amdgcn_perm(__builtin_bit_cast(unsigned, hi),
                               __builtin_bit_cast(unsigned, lo), 0x07060302u);
}

// ---------------------------------------------------------------------------
// Fused preprocessing: every block self-probes Wqkv dtype (fp32 reinterpreted
// as bf16 shows huge/NaN low-half words; 1024 samples -> P(miss) ~ 1e-26),
// so no separate probe kernel / flag dependency. Block 0 publishes the flag
// for the downstream GEMMs (stream-ordered). bid<4096: 32x32 transpose tiles
// (bx<96: Wqkv[1024,3072]->WqkvT; else Wout->WoutT). bid>=4096: X->bf16.
// ---------------------------------------------------------------------------
__global__ __launch_bounds__(256)
void preprocess(const void* __restrict__ Wqkv, bf16_t* __restrict__ WqkvT,
                const void* __restrict__ Wout, bf16_t* __restrict__ WoutT,
                const void* __restrict__ Xv, bf16_t* __restrict__ Xb,
                int* __restrict__ flag) {
  __shared__ int sbad;
  __shared__ float tile[32][33];
  const int tid = threadIdx.x;
  const int bid = blockIdx.x;
  if (tid == 0) sbad = 0;
  __syncthreads();
  {
    int bad = 0;
    const unsigned short* wp = (const unsigned short*)Wqkv;
#pragma unroll
    for (int j = 0; j < 4; ++j) {
      float f = __uint_as_float((unsigned)wp[tid + j * 256] << 16);
      if (!(fabsf(f) <= 1e10f)) bad = 1;
    }
    if (bad) sbad = 1;  // benign race: same value
  }
  __syncthreads();
  const int isf = sbad;
  if (bid == 0 && tid == 0) *flag = isf;

  if (bid < 4096) {
    int bx = bid & 127;
    const int by = bid >> 7;
    const int tx = tid & 31, ty = tid >> 5;
    const void* Wv;
    bf16_t* Wt;
    int C;
    if (bx < 96) {
      Wv = Wqkv; Wt = WqkvT; C = 3072;
    } else {
      bx -= 96; Wv = Wout; Wt = WoutT; C = 1024;
    }
    const int n0 = bx * 32, k0 = by * 32;
#pragma unroll
    for (int j = 0; j < 4; ++j) {
      const int k = k0 + ty + j * 8;
      tile[ty + j * 8][tx] =
          isf ? ((const float*)Wv)[(size_t)k * C + n0 + tx]
              : __bfloat162float(((const bf16_t*)Wv)[(size_t)k * C + n0 + tx]);
    }
    __syncthreads();
#pragma unroll
    for (int j = 0; j < 4; ++j) {
      const int n = n0 + ty + j * 8;
      Wt[(size_t)n * 1024 + k0 + tx] = __float2bfloat16(tile[tx][ty + j * 8]);
    }
  } else {
    const int i = ((bid - 4096) * 256 + tid) * 4;
    if (isf) {
      const float4 v = *(const float4*)((const float*)Xv + i);
      Xb[i + 0] = __float2bfloat16(v.x);
      Xb[i + 1] = __float2bfloat16(v.y);
      Xb[i + 2] = __float2bfloat16(v.z);
      Xb[i + 3] = __float2bfloat16(v.w);
    } else {
      *(uint2*)(Xb + i) = *(const uint2*)((const bf16_t*)Xv + i);
    }
  }
}

// ---------------------------------------------------------------------------
// C[M,N] = A[M,K] * Bt[N,K]^T + bias.  A,Bt bf16; bias/C dtype per flag.
// 128x128 tile, 4 waves, XOR-swizzled LDS, 2-phase double-buffer (r6: next
// K-tile's glds16 issued BEFORE compute, one barrier per K-step). Staging
// addresses hoisted. MODE 0: store C. MODE 1: scatter Q (CSC-scaled), K, V^T.
// ---------------------------------------------------------------------------
template <int MODE>
__global__ __launch_bounds__(256)
void gemm_k(const bf16_t* __restrict__ A, const bf16_t* __restrict__ Bt,
            const void* __restrict__ biasv, void* __restrict__ Cv,
            bf16_t* __restrict__ Qo, bf16_t* __restrict__ Ko,
            bf16_t* __restrict__ Vo, int M, int N, int K,
            const int* __restrict__ flag) {
  constexpr float CSC = 0.18033688011112042f;  // (1/sqrt(64)) * log2(e)
  __shared__ __align__(16) bf16_t lA[2][128 * 64];
  __shared__ __align__(16) bf16_t lB[2][128 * 64];

  const int isf32 = *flag;
  const int tid  = threadIdx.x;
  const int w    = tid >> 6;
  const int lane = tid & 63;
  const int lrow = lane & 15;
  const int quad = lane >> 4;
  const int m0 = blockIdx.x * 128;
  const int n0 = blockIdx.y * 128;
  const int wm = (w >> 1) * 64;
  const int wn = (w & 1) * 64;

  f32x4 acc[4][4];
  for (int i = 0; i < 4; ++i)
    for (int j = 0; j < 4; ++j)
      for (int r = 0; r < 4; ++r) acc[i][j][r] = 0.f;

  // hoisted per-lane staging offsets (bytes); per K-step just += kt*2
  const char* Ab = (const char*)A;
  const char* Bb = (const char*)Bt;
  unsigned aoff[4], boff[4];
  int ldst[4];
#pragma unroll
  for (int i = 0; i < 4; ++i) {
    const int cbase = i * 256 + w * 64;
    const int c = cbase + lane;
    const int row = c >> 3;
    const int q = (c & 7) ^ (row & 7);
    aoff[i] = (unsigned)((m0 + row) * K + q * 8) * 2u;
    boff[i] = (unsigned)((n0 + row) * K + q * 8) * 2u;
    ldst[i] = cbase * 16;
  }

  auto stage = [&](int buf, int kt) {
    const unsigned kb = (unsigned)kt * 2u;
#pragma unroll
    for (int i = 0; i < 4; ++i) {
      glds16(Ab + aoff[i] + kb, (const char*)lA[buf] + ldst[i]);
      glds16(Bb + boff[i] + kb, (const char*)lB[buf] + ldst[i]);
    }
  };

  stage(0, 0);
  __syncthreads();  // drains vmcnt: buf0 ready

  int buf = 0;
  for (int kt = 0; kt < K; kt += 64) {
    if (kt + 64 < K) stage(buf ^ 1, kt + 64);  // in flight during compute
    const char* la = (const char*)lA[buf];
    const char* lb = (const char*)lB[buf];
#pragma unroll
    for (int ks = 0; ks < 2; ++ks) {
      short8 af[4], bfr[4];
#pragma unroll
      for (int mi = 0; mi < 4; ++mi) {
        const int row = wm + mi * 16 + lrow;
        const int slot = (ks * 4 + quad) ^ (row & 7);
        af[mi] = *(const short8*)(la + row * 128 + slot * 16);
      }
#pragma unroll
      for (int ni = 0; ni < 4; ++ni) {
        const int row = wn + ni * 16 + lrow;
        const int slot = (ks * 4 + quad) ^ (row & 7);
        bfr[ni] = *(const short8*)(lb + row * 128 + slot * 16);
      }
#pragma unroll
      for (int mi = 0; mi < 4; ++mi)
#pragma unroll
        for (int ni = 0; ni < 4; ++ni)
          acc[mi][ni] = __builtin_amdgcn_mfma_f32_16x16x32_bf16(
              af[mi], bfr[ni], acc[mi][ni], 0, 0, 0);
    }
    __syncthreads();  // next buf ready; this buf's readers done (WAR-safe)
    buf ^= 1;
  }

  // epilogue: C/D layout col=lane&15, row=quad*4+reg
  if (MODE == 1) {
    const int sec = n0 >> 10;          // block-uniform
    const int b = m0 >> 11;            // block-uniform
    const int s0 = (m0 & 2047) + wm + quad * 4;
#pragma unroll
    for (int mi = 0; mi < 4; ++mi) {
#pragma unroll
      for (int ni = 0; ni < 4; ++ni) {
        const int col = n0 + wn + ni * 16 + lrow;
        const float bv = isf32 ? ((const float*)biasv)[col]
                               : __bfloat162float(((const bf16_t*)biasv)[col]);
        const int h = (col >> 6) & 15, d = col & 63;
        const int s = s0 + mi * 16;
        if (sec == 2) {  // V^T[bh][d][s]: 4 consecutive s -> one 8B store
          short4v hv4;
#pragma unroll
          for (int r = 0; r < 4; ++r) hv4[r] = bfbits(acc[mi][ni][r] + bv);
          *(short4v*)(Vo + ((((size_t)b * 16 + h) * 64) + d) * 2048 + s) = hv4;
        } else if (sec == 0) {  // Q, pre-scaled by CSC
          bf16_t* dst = Qo + ((((size_t)b * 16 + h) * 2048) + s) * 64 + d;
#pragma unroll
          for (int r = 0; r < 4; ++r)
            dst[(size_t)r * 64] = __float2bfloat16((acc[mi][ni][r] + bv) * CSC);
        } else {
          bf16_t* dst = Ko + ((((size_t)b * 16 + h) * 2048) + s) * 64 + d;
#pragma unroll
          for (int r = 0; r < 4; ++r)
            dst[(size_t)r * 64] = __float2bfloat16(acc[mi][ni][r] + bv);
        }
      }
    }
  } else {
#pragma unroll
    for (int mi = 0; mi < 4; ++mi) {
#pragma unroll
      for (int ni = 0; ni < 4; ++ni) {
        const int col = n0 + wn + ni * 16 + lrow;
        const float bv = isf32 ? ((const float*)biasv)[col]
                               : __bfloat162float(((const bf16_t*)biasv)[col]);
#pragma unroll
        for (int r = 0; r < 4; ++r) {
          const int row = m0 + wm + mi * 16 + quad * 4 + r;
          const float val = acc[mi][ni][r] + bv;
          if (isf32)
            ((float*)Cv)[(size_t)row * N + col] = val;
          else
            ((bf16_t*)Cv)[(size_t)row * N + col] = __float2bfloat16(val);
        }
      }
    }
  }
}

// ---------------------------------------------------------------------------
// Flash attention: transposed-score + x32-PV + glds16 double-buffer, qt=4.
// r7: revert to the r5-measured loop/staging structure (r6's chunk-indexed
// loop + hoisted offsets regressed 72.2->75.8), plus QK-hoist pipeline:
// QK^T for BOTH 32-key halves first (32-MFMA independent run), then per-half
// {exp2+pack -> lsacc+PV}. exp2(g0) gets a long MFMA gap (no result stall);
// exp2(g1) on the trans pipe issues while PV(g0) drains the matrix pipe.
// Pure reorder of commutative accumulations - numerics identical.
// ---------------------------------------------------------------------------
__global__ __launch_bounds__(256, 2)
void attn_fwd(const bf16_t* __restrict__ Q, const bf16_t* __restrict__ K,
              const bf16_t* __restrict__ Vt, bf16_t* __restrict__ AO) {
  __shared__ __align__(16) bf16_t lK[2][64 * 64];  // [key][d], fk(row) swizzle
  __shared__ __align__(16) bf16_t lV[2][64 * 64];  // [d][key], row&7 swizzle

  const int tid  = threadIdx.x;
  const int w    = tid >> 6;
  const int lane = tid & 63;
  const int lrow = lane & 15;
  const int quad = lane >> 4;
  const int id = blockIdx.x;
  const int swz = (id & 7) * 64 + (id >> 3);  // XCD-contiguous bh chunks
  const int bh  = swz >> 3;
  const int q0  = (swz & 7) * 256;

  const bf16_t* Qb = Q + (size_t)bh * 2048 * 64;
  const bf16_t* Kb = K + (size_t)bh * 2048 * 64;
  const bf16_t* Vb = Vt + (size_t)bh * 64 * 2048;

  // per-lane constants for permuted K-frag reads
  const int rbase = (lrow >> 2) * 8 + (lrow & 3);
  const int fkl   = 2 * (lrow >> 2) + (lrow & 1);

  // Q fragments (B-operand): lane holds Q[q=lrow][d=ks*32+quad*8+j]
  short8 aq[4][2];
#pragma unroll
  for (int qt = 0; qt < 4; ++qt)
#pragma unroll
    for (int ks = 0; ks < 2; ++ks)
      aq[qt][ks] = *(const short8*)(Qb +
          (size_t)(q0 + w * 64 + qt * 16 + lrow) * 64 + ks * 32 + quad * 8);

  short8 ones;
#pragma unroll
  for (int j = 0; j < 8; ++j) ones[j] = (short)0x3F80;  // bf16 1.0

  const f32x4 zf = {0.f, 0.f, 0.f, 0.f};  // shared zero C-operand

  f32x4 ot[4][4];   // O^T[d-tile][q-tile]: d=quad*4+r, q=lrow
  f32x4 lsacc[4];   // sum-of-p per q (replicated over quads)
#pragma unroll
  for (int dt = 0; dt < 4; ++dt)
#pragma unroll
    for (int qt = 0; qt < 4; ++qt)
#pragma unroll
      for (int r = 0; r < 4; ++r) ot[dt][qt][r] = 0.f;
#pragma unroll
  for (int qt = 0; qt < 4; ++qt)
#pragma unroll
    for (int r = 0; r < 4; ++r) lsacc[qt][r] = 0.f;

  // async staging: global source carries the XOR swizzle; LDS is lane-linear
  auto stage = [&](int buf, int kt) {
#pragma unroll
    for (int i = 0; i < 2; ++i) {
      const int cbase = i * 256 + w * 64;
      const int c = cbase + lane;
      const int row = c >> 3, ch = c & 7;
      const int fk = 2 * ((row >> 3) & 3) + (row & 1);
      glds16(Kb + (size_t)(kt + row) * 64 + (ch ^ fk) * 8,
             (const char*)lK[buf] + cbase * 16);
      glds16(Vb + (size_t)row * 2048 + kt + (ch ^ (row & 7)) * 8,
             (const char*)lV[buf] + cbase * 16);
    }
  };

  auto compute = [&](const bf16_t* lKb, const bf16_t* lVb) {
    f32x4 sc[2][2][4];  // [g][T][qt], both halves live across QK cluster
#pragma unroll
    for (int g = 0; g < 2; ++g) {
      short8 ak0[2], ak1[2];
#pragma unroll
      for (int T = 0; T < 2; ++T) {
        const int row = g * 32 + T * 4 + rbase;
        ak0[T] = *(const short8*)((const char*)lKb + row * 128 +
                                  ((0 * 4 + quad) ^ fkl) * 16);
        ak1[T] = *(const short8*)((const char*)lKb + row * 128 +
                                  ((1 * 4 + quad) ^ fkl) * 16);
      }
      __builtin_amdgcn_s_setprio(1);
#pragma unroll
      for (int T = 0; T < 2; ++T)
#pragma unroll
        for (int qt = 0; qt < 4; ++qt)
          sc[g][T][qt] = __builtin_amdgcn_mfma_f32_16x16x32_bf16(
              ak0[T], aq[qt][0], zf, 0, 0, 0);  // zero-C: no sc pre-init
#pragma unroll
      for (int T = 0; T < 2; ++T)
#pragma unroll
        for (int qt = 0; qt < 4; ++qt)
          sc[g][T][qt] = __builtin_amdgcn_mfma_f32_16x16x32_bf16(
              ak1[T], aq[qt][1], sc[g][T][qt], 0, 0, 0);
      __builtin_amdgcn_s_setprio(0);
    }
    // per-half: softmax (trans pipe) then lsacc+PV (matrix pipe); the g=1
    // exp2 run issues while g=0's PV is still draining the matrix pipe.
#pragma unroll
    for (int g = 0; g < 2; ++g) {
      short8 pb[4];
#pragma unroll
      for (int qt = 0; qt < 4; ++qt) {
        float p[8];
#pragma unroll
        for (int T = 0; T < 2; ++T)
#pragma unroll
          for (int r = 0; r < 4; ++r)
            p[T * 4 + r] = __builtin_amdgcn_exp2f(sc[g][T][qt][r]);
        int4v pi = {pk2(p[0], p[1]), pk2(p[2], p[3]), pk2(p[4], p[5]),
                    pk2(p[6], p[7])};
        pb[qt] = __builtin_bit_cast(short8, pi);
      }

      __builtin_amdgcn_s_setprio(1);
#pragma unroll
      for (int qt = 0; qt < 4; ++qt)
        lsacc[qt] = __builtin_amdgcn_mfma_f32_16x16x32_bf16(ones, pb[qt],
                                                            lsacc[qt], 0, 0, 0);
#pragma unroll
      for (int dt = 0; dt < 4; ++dt) {
        const int row = dt * 16 + lrow;
        const int slot = (g * 4 + quad) ^ (row & 7);
        const short8 vf =
            *(const short8*)((const char*)lVb + row * 128 + slot * 16);
#pragma unroll
        for (int qt = 0; qt < 4; ++qt)
          ot[dt][qt] = __builtin_amdgcn_mfma_f32_16x16x32_bf16(
              vf, pb[qt], ot[dt][qt], 0, 0, 0);
      }
      __builtin_amdgcn_s_setprio(0);
    }
  };

  stage(0, 0);
  __syncthreads();  // drains vmcnt: buf0 ready

  for (int kt = 0; kt < 2048; kt += 128) {
    if (kt + 64 < 2048) stage(1, kt + 64);   // in flight during compute
    compute(lK[0], lV[0]);
    __syncthreads();                          // buf1 ready; buf0 readers done
    if (kt + 128 < 2048) stage(0, kt + 128);
    compute(lK[1], lV[1]);
    __syncthreads();
  }

  // scale + store O^T -> AO[b*2048+s][h*64+d]
  const int b = bh >> 4, h = bh & 15;
#pragma unroll
  for (int qt = 0; qt < 4; ++qt) {
    const float inv = 1.f / lsacc[qt][0];
    const int srow = q0 + w * 64 + qt * 16 + lrow;
#pragma unroll
    for (int dt = 0; dt < 4; ++dt) {
      uint2 pack;
      short* ps = (short*)&pack;
#pragma unroll
      for (int r = 0; r < 4; ++r) ps[r] = bfbits(ot[dt][qt][r] * inv);
      *(uint2*)(AO + ((size_t)b * 2048 + srow) * 1024 + h * 64 + dt * 16 +
                quad * 4) = pack;
    }
  }
}

// ---------------------------------------------------------------------------
extern "C" void kernel_launch(void* const* d_in, const int* in_sizes, int n_in,
                              void* d_out, int out_size, void* d_ws,
                              size_t ws_size, hipStream_t stream) {
  const void* X    = d_in[0];
  const void* Wqkv = d_in[1];
  const void* bqkv = d_in[2];
  const void* Wout = d_in[3];
  const void* bout = d_in[4];

  char* ws = (char*)d_ws;
  bf16_t* WqkvT = (bf16_t*)(ws);               // [3072,1024]  6 MB
  bf16_t* WoutT = (bf16_t*)(ws + 6291456);     // [1024,1024]  2 MB
  bf16_t* Qw    = (bf16_t*)(ws + 8388608);     // [64,2048,64] 16 MB
  bf16_t* Kw    = (bf16_t*)(ws + 25165824);    // [64,2048,64] 16 MB
  bf16_t* Vw    = (bf16_t*)(ws + 41943040);    // [64,64,2048] 16 MB (V^T)
  bf16_t* AOw   = (bf16_t*)(ws + 58720256);    // [8192,1024]  16 MB
  bf16_t* Xbf   = AOw;  // aliases AOw: Xbf dead before attn writes AOw
  int*    flag  = (int*)(ws + 75497472);

  preprocess<<<12288, 256, 0, stream>>>(Wqkv, WqkvT, Wout, WoutT, X, Xbf, flag);

  gemm_k<1><<<dim3(64, 24), 256, 0, stream>>>(Xbf, WqkvT, bqkv, nullptr, Qw,
                                              Kw, Vw, 8192, 3072, 1024, flag);
  attn_fwd<<<512, 256, 0, stream>>>(Qw, Kw, Vw, AOw);
  gemm_k<0><<<dim3(64, 8), 256, 0, stream>>>(AOw, WoutT, bout, d_out, nullptr,
                                             nullptr, nullptr, 8192, 1024, 1024,
                                             flag);
}

// Round 8
// 249.849 us; speedup vs baseline: 1.0331x; 1.0331x over previous
//
#include <hip/hip_runtime.h>
#include <hip/hip_bf16.h>
#include <stdint.h>
#include <stddef.h>

using short8  = __attribute__((ext_vector_type(8))) short;
using short4v = __attribute__((ext_vector_type(4))) short;
using int4v   = __attribute__((ext_vector_type(4))) int;
using f32x4   = __attribute__((ext_vector_type(4))) float;
typedef __hip_bfloat16 bf16_t;

__device__ __forceinline__ void glds16(const void* g, const void* l) {
  __builtin_amdgcn_global_load_lds(
      (const __attribute__((address_space(1))) void*)g,
      (__attribute__((address_space(3))) void*)l, 16, 0, 0);
}
__device__ __forceinline__ short bfbits(float x) {
  bf16_t h = __float2bfloat16(x);
  return __builtin_bit_cast(short, h);
}
// pack two fp32 -> two bf16 (RTZ) in one v_perm_b32
__device__ __forceinline__ int pk2(float lo, float hi) {
  return __builtin_amdgcn_perm(__builtin_bit_cast(unsigned, hi),
                               __builtin_bit_cast(unsigned, lo), 0x07060302u);
}

// ---------------------------------------------------------------------------
// Fused preprocessing: every block self-probes Wqkv dtype (fp32 reinterpreted
// as bf16 shows huge/NaN low-half words; 1024 samples -> P(miss) ~ 1e-26),
// so no separate probe kernel / flag dependency. Block 0 publishes the flag
// for the downstream GEMMs (stream-ordered). bid<4096: 32x32 transpose tiles
// (bx<96: Wqkv[1024,3072]->WqkvT; else Wout->WoutT). bid>=4096: X->bf16.
// ---------------------------------------------------------------------------
__global__ __launch_bounds__(256)
void preprocess(const void* __restrict__ Wqkv, bf16_t* __restrict__ WqkvT,
                const void* __restrict__ Wout, bf16_t* __restrict__ WoutT,
                const void* __restrict__ Xv, bf16_t* __restrict__ Xb,
                int* __restrict__ flag) {
  __shared__ int sbad;
  __shared__ float tile[32][33];
  const int tid = threadIdx.x;
  const int bid = blockIdx.x;
  if (tid == 0) sbad = 0;
  __syncthreads();
  {
    int bad = 0;
    const unsigned short* wp = (const unsigned short*)Wqkv;
#pragma unroll
    for (int j = 0; j < 4; ++j) {
      float f = __uint_as_float((unsigned)wp[tid + j * 256] << 16);
      if (!(fabsf(f) <= 1e10f)) bad = 1;
    }
    if (bad) sbad = 1;  // benign race: same value
  }
  __syncthreads();
  const int isf = sbad;
  if (bid == 0 && tid == 0) *flag = isf;

  if (bid < 4096) {
    int bx = bid & 127;
    const int by = bid >> 7;
    const int tx = tid & 31, ty = tid >> 5;
    const void* Wv;
    bf16_t* Wt;
    int C;
    if (bx < 96) {
      Wv = Wqkv; Wt = WqkvT; C = 3072;
    } else {
      bx -= 96; Wv = Wout; Wt = WoutT; C = 1024;
    }
    const int n0 = bx * 32, k0 = by * 32;
#pragma unroll
    for (int j = 0; j < 4; ++j) {
      const int k = k0 + ty + j * 8;
      tile[ty + j * 8][tx] =
          isf ? ((const float*)Wv)[(size_t)k * C + n0 + tx]
              : __bfloat162float(((const bf16_t*)Wv)[(size_t)k * C + n0 + tx]);
    }
    __syncthreads();
#pragma unroll
    for (int j = 0; j < 4; ++j) {
      const int n = n0 + ty + j * 8;
      Wt[(size_t)n * 1024 + k0 + tx] = __float2bfloat16(tile[tx][ty + j * 8]);
    }
  } else {
    const int i = ((bid - 4096) * 256 + tid) * 4;
    if (isf) {
      const float4 v = *(const float4*)((const float*)Xv + i);
      Xb[i + 0] = __float2bfloat16(v.x);
      Xb[i + 1] = __float2bfloat16(v.y);
      Xb[i + 2] = __float2bfloat16(v.z);
      Xb[i + 3] = __float2bfloat16(v.w);
    } else {
      *(uint2*)(Xb + i) = *(const uint2*)((const bf16_t*)Xv + i);
    }
  }
}

// ---------------------------------------------------------------------------
// C[M,N] = A[M,K] * Bt[N,K]^T + bias.  A,Bt bf16; bias/C dtype per flag.
// r8: 256x128 tile, 512 threads (8 waves = 4M x 2N of 64x64 wave-tiles).
// r7 profile showed the 128^2 GEMM is L2-BANDWIDTH-BOUND on glds16 staging
// (predicted MfmaUtil from L2 feed rate = 27%, measured 28-30% across three
// structural variants). 256x128 cuts staged bytes/FLOP 25% (11.7 vs 15.6
// B/kFLOP) and makes grids exact: 32x24=768=3 rounds, 32x8=256=1 round.
// Per-wave compute/epilogue identical to the proven r5 kernel. Single-buffer
// LDS 48KB (2 blocks/CU), hoisted staging addresses.
// MODE 0: store C.  MODE 1: scatter to Q (pre-scaled by CSC), K, V^T bf16.
// ---------------------------------------------------------------------------
template <int MODE>
__global__ __launch_bounds__(512)
void gemm_k(const bf16_t* __restrict__ A, const bf16_t* __restrict__ Bt,
            const void* __restrict__ biasv, void* __restrict__ Cv,
            bf16_t* __restrict__ Qo, bf16_t* __restrict__ Ko,
            bf16_t* __restrict__ Vo, int M, int N, int K,
            const int* __restrict__ flag) {
  constexpr float CSC = 0.18033688011112042f;  // (1/sqrt(64)) * log2(e)
  __shared__ __align__(16) bf16_t lA[256 * 64];  // 32 KB
  __shared__ __align__(16) bf16_t lB[128 * 64];  // 16 KB

  const int isf32 = *flag;
  const int tid  = threadIdx.x;
  const int w    = tid >> 6;
  const int lane = tid & 63;
  const int lrow = lane & 15;
  const int quad = lane >> 4;
  const int m0 = blockIdx.x * 256;
  const int n0 = blockIdx.y * 128;
  const int wm = (w >> 1) * 64;   // 0..192
  const int wn = (w & 1) * 64;    // 0..64

  f32x4 acc[4][4];
  for (int i = 0; i < 4; ++i)
    for (int j = 0; j < 4; ++j)
      for (int r = 0; r < 4; ++r) acc[i][j][r] = 0.f;

  // hoisted per-lane staging offsets (bytes); per K-step just += kt*2
  const char* Ab = (const char*)A;
  const char* Bb = (const char*)Bt;
  unsigned aoff[4], boff[2];
  int lda[4], ldb[2];
#pragma unroll
  for (int i = 0; i < 4; ++i) {  // A: 256 rows x 8 chunks = 2048 / 512 thr
    const int c = i * 512 + tid;
    const int row = c >> 3;
    const int q = (c & 7) ^ (row & 7);
    aoff[i] = (unsigned)((m0 + row) * K + q * 8) * 2u;
    lda[i] = c * 16;
  }
#pragma unroll
  for (int i = 0; i < 2; ++i) {  // B: 128 rows x 8 chunks = 1024 / 512 thr
    const int c = i * 512 + tid;
    const int row = c >> 3;
    const int q = (c & 7) ^ (row & 7);
    boff[i] = (unsigned)((n0 + row) * K + q * 8) * 2u;
    ldb[i] = c * 16;
  }

  auto stage = [&](int kt) {
    const unsigned kb = (unsigned)kt * 2u;
#pragma unroll
    for (int i = 0; i < 4; ++i)
      glds16(Ab + aoff[i] + kb, (const char*)lA + lda[i]);
#pragma unroll
    for (int i = 0; i < 2; ++i)
      glds16(Bb + boff[i] + kb, (const char*)lB + ldb[i]);
  };

  for (int kt = 0; kt < K; kt += 64) {
    stage(kt);
    __syncthreads();  // drains vmcnt: tile ready
#pragma unroll
    for (int ks = 0; ks < 2; ++ks) {
      short8 af[4], bfr[4];
#pragma unroll
      for (int mi = 0; mi < 4; ++mi) {
        const int row = wm + mi * 16 + lrow;
        const int slot = (ks * 4 + quad) ^ (row & 7);
        af[mi] = *(const short8*)((const char*)lA + row * 128 + slot * 16);
      }
#pragma unroll
      for (int ni = 0; ni < 4; ++ni) {
        const int row = wn + ni * 16 + lrow;
        const int slot = (ks * 4 + quad) ^ (row & 7);
        bfr[ni] = *(const short8*)((const char*)lB + row * 128 + slot * 16);
      }
#pragma unroll
      for (int mi = 0; mi < 4; ++mi)
#pragma unroll
        for (int ni = 0; ni < 4; ++ni)
          acc[mi][ni] = __builtin_amdgcn_mfma_f32_16x16x32_bf16(
              af[mi], bfr[ni], acc[mi][ni], 0, 0, 0);
    }
    __syncthreads();  // readers done before next stage overwrites (WAR)
  }

  // epilogue: C/D layout col=lane&15, row=quad*4+reg
  if (MODE == 1) {
    const int sec = n0 >> 10;          // block-uniform (BN=128, 1024-aligned)
    const int b = m0 >> 11;            // block-uniform
    const int s0 = (m0 & 2047) + wm + quad * 4;
#pragma unroll
    for (int mi = 0; mi < 4; ++mi) {
#pragma unroll
      for (int ni = 0; ni < 4; ++ni) {
        const int col = n0 + wn + ni * 16 + lrow;
        const float bv = isf32 ? ((const float*)biasv)[col]
                               : __bfloat162float(((const bf16_t*)biasv)[col]);
        const int h = (col >> 6) & 15, d = col & 63;
        const int s = s0 + mi * 16;
        if (sec == 2) {  // V^T[bh][d][s]: 4 consecutive s -> one 8B store
          short4v hv4;
#pragma unroll
          for (int r = 0; r < 4; ++r) hv4[r] = bfbits(acc[mi][ni][r] + bv);
          *(short4v*)(Vo + ((((size_t)b * 16 + h) * 64) + d) * 2048 + s) = hv4;
        } else if (sec == 0) {  // Q, pre-scaled by CSC
          bf16_t* dst = Qo + ((((size_t)b * 16 + h) * 2048) + s) * 64 + d;
#pragma unroll
          for (int r = 0; r < 4; ++r)
            dst[(size_t)r * 64] = __float2bfloat16((acc[mi][ni][r] + bv) * CSC);
        } else {
          bf16_t* dst = Ko + ((((size_t)b * 16 + h) * 2048) + s) * 64 + d;
#pragma unroll
          for (int r = 0; r < 4; ++r)
            dst[(size_t)r * 64] = __float2bfloat16(acc[mi][ni][r] + bv);
        }
      }
    }
  } else {
#pragma unroll
    for (int mi = 0; mi < 4; ++mi) {
#pragma unroll
      for (int ni = 0; ni < 4; ++ni) {
        const int col = n0 + wn + ni * 16 + lrow;
        const float bv = isf32 ? ((const float*)biasv)[col]
                               : __bfloat162float(((const bf16_t*)biasv)[col]);
#pragma unroll
        for (int r = 0; r < 4; ++r) {
          const int row = m0 + wm + mi * 16 + quad * 4 + r;
          const float val = acc[mi][ni][r] + bv;
          if (isf32)
            ((float*)Cv)[(size_t)row * N + col] = val;
          else
            ((bf16_t*)Cv)[(size_t)row * N + col] = __float2bfloat16(val);
        }
      }
    }
  }
}

// ---------------------------------------------------------------------------
// Flash attention: transposed-score + x32-PV + glds16 double-buffer, qt=4.
// r7 structure kept: r5 loop/staging + QK-hoist pipeline (QK^T for BOTH
// 32-key halves first, then per-half {exp2+pack -> lsacc+PV}); zero-C first
// MFMA; setprio around MFMA clusters. Not L2-bound (43% MfmaUtil).
// ---------------------------------------------------------------------------
__global__ __launch_bounds__(256, 2)
void attn_fwd(const bf16_t* __restrict__ Q, const bf16_t* __restrict__ K,
              const bf16_t* __restrict__ Vt, bf16_t* __restrict__ AO) {
  __shared__ __align__(16) bf16_t lK[2][64 * 64];  // [key][d], fk(row) swizzle
  __shared__ __align__(16) bf16_t lV[2][64 * 64];  // [d][key], row&7 swizzle

  const int tid  = threadIdx.x;
  const int w    = tid >> 6;
  const int lane = tid & 63;
  const int lrow = lane & 15;
  const int quad = lane >> 4;
  const int id = blockIdx.x;
  const int swz = (id & 7) * 64 + (id >> 3);  // XCD-contiguous bh chunks
  const int bh  = swz >> 3;
  const int q0  = (swz & 7) * 256;

  const bf16_t* Qb = Q + (size_t)bh * 2048 * 64;
  const bf16_t* Kb = K + (size_t)bh * 2048 * 64;
  const bf16_t* Vb = Vt + (size_t)bh * 64 * 2048;

  // per-lane constants for permuted K-frag reads
  const int rbase = (lrow >> 2) * 8 + (lrow & 3);
  const int fkl   = 2 * (lrow >> 2) + (lrow & 1);

  // Q fragments (B-operand): lane holds Q[q=lrow][d=ks*32+quad*8+j]
  short8 aq[4][2];
#pragma unroll
  for (int qt = 0; qt < 4; ++qt)
#pragma unroll
    for (int ks = 0; ks < 2; ++ks)
      aq[qt][ks] = *(const short8*)(Qb +
          (size_t)(q0 + w * 64 + qt * 16 + lrow) * 64 + ks * 32 + quad * 8);

  short8 ones;
#pragma unroll
  for (int j = 0; j < 8; ++j) ones[j] = (short)0x3F80;  // bf16 1.0

  const f32x4 zf = {0.f, 0.f, 0.f, 0.f};  // shared zero C-operand

  f32x4 ot[4][4];   // O^T[d-tile][q-tile]: d=quad*4+r, q=lrow
  f32x4 lsacc[4];   // sum-of-p per q (replicated over quads)
#pragma unroll
  for (int dt = 0; dt < 4; ++dt)
#pragma unroll
    for (int qt = 0; qt < 4; ++qt)
#pragma unroll
      for (int r = 0; r < 4; ++r) ot[dt][qt][r] = 0.f;
#pragma unroll
  for (int qt = 0; qt < 4; ++qt)
#pragma unroll
    for (int r = 0; r < 4; ++r) lsacc[qt][r] = 0.f;

  // async staging: global source carries the XOR swizzle; LDS is lane-linear
  auto stage = [&](int buf, int kt) {
#pragma unroll
    for (int i = 0; i < 2; ++i) {
      const int cbase = i * 256 + w * 64;
      const int c = cbase + lane;
      const int row = c >> 3, ch = c & 7;
      const int fk = 2 * ((row >> 3) & 3) + (row & 1);
      glds16(Kb + (size_t)(kt + row) * 64 + (ch ^ fk) * 8,
             (const char*)lK[buf] + cbase * 16);
      glds16(Vb + (size_t)row * 2048 + kt + (ch ^ (row & 7)) * 8,
             (const char*)lV[buf] + cbase * 16);
    }
  };

  auto compute = [&](const bf16_t* lKb, const bf16_t* lVb) {
    f32x4 sc[2][2][4];  // [g][T][qt], both halves live across QK cluster
#pragma unroll
    for (int g = 0; g < 2; ++g) {
      short8 ak0[2], ak1[2];
#pragma unroll
      for (int T = 0; T < 2; ++T) {
        const int row = g * 32 + T * 4 + rbase;
        ak0[T] = *(const short8*)((const char*)lKb + row * 128 +
                                  ((0 * 4 + quad) ^ fkl) * 16);
        ak1[T] = *(const short8*)((const char*)lKb + row * 128 +
                                  ((1 * 4 + quad) ^ fkl) * 16);
      }
      __builtin_amdgcn_s_setprio(1);
#pragma unroll
      for (int T = 0; T < 2; ++T)
#pragma unroll
        for (int qt = 0; qt < 4; ++qt)
          sc[g][T][qt] = __builtin_amdgcn_mfma_f32_16x16x32_bf16(
              ak0[T], aq[qt][0], zf, 0, 0, 0);  // zero-C: no sc pre-init
#pragma unroll
      for (int T = 0; T < 2; ++T)
#pragma unroll
        for (int qt = 0; qt < 4; ++qt)
          sc[g][T][qt] = __builtin_amdgcn_mfma_f32_16x16x32_bf16(
              ak1[T], aq[qt][1], sc[g][T][qt], 0, 0, 0);
      __builtin_amdgcn_s_setprio(0);
    }
    // per-half: softmax (trans pipe) then lsacc+PV (matrix pipe); the g=1
    // exp2 run issues while g=0's PV is still draining the matrix pipe.
#pragma unroll
    for (int g = 0; g < 2; ++g) {
      short8 pb[4];
#pragma unroll
      for (int qt = 0; qt < 4; ++qt) {
        float p[8];
#pragma unroll
        for (int T = 0; T < 2; ++T)
#pragma unroll
          for (int r = 0; r < 4; ++r)
            p[T * 4 + r] = __builtin_amdgcn_exp2f(sc[g][T][qt][r]);
        int4v pi = {pk2(p[0], p[1]), pk2(p[2], p[3]), pk2(p[4], p[5]),
                    pk2(p[6], p[7])};
        pb[qt] = __builtin_bit_cast(short8, pi);
      }

      __builtin_amdgcn_s_setprio(1);
#pragma unroll
      for (int qt = 0; qt < 4; ++qt)
        lsacc[qt] = __builtin_amdgcn_mfma_f32_16x16x32_bf16(ones, pb[qt],
                                                            lsacc[qt], 0, 0, 0);
#pragma unroll
      for (int dt = 0; dt < 4; ++dt) {
        const int row = dt * 16 + lrow;
        const int slot = (g * 4 + quad) ^ (row & 7);
        const short8 vf =
            *(const short8*)((const char*)lVb + row * 128 + slot * 16);
#pragma unroll
        for (int qt = 0; qt < 4; ++qt)
          ot[dt][qt] = __builtin_amdgcn_mfma_f32_16x16x32_bf16(
              vf, pb[qt], ot[dt][qt], 0, 0, 0);
      }
      __builtin_amdgcn_s_setprio(0);
    }
  };

  stage(0, 0);
  __syncthreads();  // drains vmcnt: buf0 ready

  for (int kt = 0; kt < 2048; kt += 128) {
    if (kt + 64 < 2048) stage(1, kt + 64);   // in flight during compute
    compute(lK[0], lV[0]);
    __syncthreads();                          // buf1 ready; buf0 readers done
    if (kt + 128 < 2048) stage(0, kt + 128);
    compute(lK[1], lV[1]);
    __syncthreads();
  }

  // scale + store O^T -> AO[b*2048+s][h*64+d]
  const int b = bh >> 4, h = bh & 15;
#pragma unroll
  for (int qt = 0; qt < 4; ++qt) {
    const float inv = 1.f / lsacc[qt][0];
    const int srow = q0 + w * 64 + qt * 16 + lrow;
#pragma unroll
    for (int dt = 0; dt < 4; ++dt) {
      uint2 pack;
      short* ps = (short*)&pack;
#pragma unroll
      for (int r = 0; r < 4; ++r) ps[r] = bfbits(ot[dt][qt][r] * inv);
      *(uint2*)(AO + ((size_t)b * 2048 + srow) * 1024 + h * 64 + dt * 16 +
                quad * 4) = pack;
    }
  }
}

// ---------------------------------------------------------------------------
extern "C" void kernel_launch(void* const* d_in, const int* in_sizes, int n_in,
                              void* d_out, int out_size, void* d_ws,
                              size_t ws_size, hipStream_t stream) {
  const void* X    = d_in[0];
  const void* Wqkv = d_in[1];
  const void* bqkv = d_in[2];
  const void* Wout = d_in[3];
  const void* bout = d_in[4];

  char* ws = (char*)d_ws;
  bf16_t* WqkvT = (bf16_t*)(ws);               // [3072,1024]  6 MB
  bf16_t* WoutT = (bf16_t*)(ws + 6291456);     // [1024,1024]  2 MB
  bf16_t* Qw    = (bf16_t*)(ws + 8388608);     // [64,2048,64] 16 MB
  bf16_t* Kw    = (bf16_t*)(ws + 25165824);    // [64,2048,64] 16 MB
  bf16_t* Vw    = (bf16_t*)(ws + 41943040);    // [64,64,2048] 16 MB (V^T)
  bf16_t* AOw   = (bf16_t*)(ws + 58720256);    // [8192,1024]  16 MB
  bf16_t* Xbf   = AOw;  // aliases AOw: Xbf dead before attn writes AOw
  int*    flag  = (int*)(ws + 75497472);

  preprocess<<<12288, 256, 0, stream>>>(Wqkv, WqkvT, Wout, WoutT, X, Xbf, flag);

  gemm_k<1><<<dim3(32, 24), 512, 0, stream>>>(Xbf, WqkvT, bqkv, nullptr, Qw,
                                              Kw, Vw, 8192, 3072, 1024, flag);
  attn_fwd<<<512, 256, 0, stream>>>(Qw, Kw, Vw, AOw);
  gemm_k<0><<<dim3(32, 8), 512, 0, stream>>>(AOw, WoutT, bout, d_out, nullptr,
                                             nullptr, nullptr, 8192, 1024, 1024,
                                             flag);
}